// Round 8
// baseline (621.515 us; speedup 1.0000x reference)
//
#include <hip/hip_runtime.h>
#include <hip/hip_bf16.h>
#include <math.h>

#define NNODES 50000
#define HID    64
#define HEADS  4
#define FDIM   256   // HEADS*HID

typedef __attribute__((ext_vector_type(8))) short short8v;
typedef __attribute__((ext_vector_type(4))) float f32x4;

__device__ __forceinline__ float lrelu(float x) { return fmaxf(x, 0.2f * x); }

__device__ __forceinline__ ushort f2bf(float x) {
  union { float f; unsigned u; } c; c.f = x;
  unsigned r = (c.u + 0x7FFF + ((c.u >> 16) & 1)) >> 16;   // RNE
  return (ushort)r;
}
__device__ __forceinline__ float bf2f(ushort h) {
  union { unsigned u; float f; } c; c.u = ((unsigned)h) << 16;
  return c.f;
}

// ---------------- f32 -> (hi,lo) bf16 split, vectorized ----------------
__global__ void split_kernel(const float4* __restrict__ x, ushort* __restrict__ hi,
                             ushort* __restrict__ lo, int n4)
{
  int t = blockIdx.x * blockDim.x + threadIdx.x;
  if (t >= n4) return;
  float4 v = x[t];
  ushort h0 = f2bf(v.x), h1 = f2bf(v.y), h2 = f2bf(v.z), h3 = f2bf(v.w);
  *(ushort4*)(hi + (size_t)t * 4) = make_ushort4(h0, h1, h2, h3);
  *(ushort4*)(lo + (size_t)t * 4) = make_ushort4(
      f2bf(v.x - bf2f(h0)), f2bf(v.y - bf2f(h1)),
      f2bf(v.z - bf2f(h2)), f2bf(v.w - bf2f(h3)));
}

// ---------------- weight transposes+splits (rows 0..255 of cat arrays) ----------------
__global__ void wtconv_all_kernel(const float* __restrict__ enc_w, const float* __restrict__ g1_w,
                                  const float* __restrict__ g2_w, const float* __restrict__ lp1_w,
                                  ushort* __restrict__ we_hi, ushort* __restrict__ we_lo,
                                  ushort* __restrict__ w1_hi, ushort* __restrict__ w1_lo,
                                  ushort* __restrict__ w2_hi, ushort* __restrict__ w2_lo,
                                  ushort* __restrict__ wlp_hi, ushort* __restrict__ wlp_lo)
{
  int t = blockIdx.x * blockDim.x + threadIdx.x;   // 0..131071
  float w; ushort* dh; ushort* dl; int di;
  if (t < 16384) {                       // enc: N=64,K=256
    int n = t >> 8, k = t & 255;
    w = enc_w[(size_t)k * 64 + n]; dh = we_hi; dl = we_lo; di = t;
  } else if (t < 32768) {                // g1: N=256,K=64
    int l = t - 16384; int n = l >> 6, k = l & 63;
    w = g1_w[(size_t)k * 256 + n]; dh = w1_hi; dl = w1_lo; di = l;
  } else if (t < 98304) {                // g2: N=256,K=256
    int l = t - 32768; int n = l >> 8, k = l & 255;
    w = g2_w[(size_t)k * 256 + n]; dh = w2_hi; dl = w2_lo; di = l;
  } else {                               // lp stacked: N=128,K=256
    int l = t - 98304; int n = l >> 8, k = l & 255;
    int srow = (n < 64) ? k : (256 + k);
    w = lp1_w[(size_t)srow * 64 + (n & 63)]; dh = wlp_hi; dl = wlp_lo; di = l;
  }
  ushort h = f2bf(w);
  dh[di] = h;
  dl[di] = f2bf(w - bf2f(h));
}

// ---------------- att-combined columns: rows 256..271 of w1cat/w2cat ----------------
__global__ void attcomb_kernel(const float* __restrict__ g1_w, const float* __restrict__ g1_as,
                               const float* __restrict__ g1_ad,
                               const float* __restrict__ g2_w, const float* __restrict__ g2_as,
                               const float* __restrict__ g2_ad,
                               ushort* __restrict__ w1_hi, ushort* __restrict__ w1_lo,
                               ushort* __restrict__ w2_hi, ushort* __restrict__ w2_lo)
{
  int t = blockIdx.x * blockDim.x + threadIdx.x;   // 0..5119
  if (t < 1024) {                        // g1: KTOT=64
    int j = t >> 6, k = t & 63;
    float v = 0.f;
    if (j < 8) {
      int head = j & 3;
      const float* att = (j < 4 ? g1_as : g1_ad) + head * 64;
      for (int c = 0; c < 64; ++c) v += g1_w[(size_t)k * 256 + head * 64 + c] * att[c];
    }
    ushort h = f2bf(v);
    w1_hi[(256 + j) * 64 + k] = h;
    w1_lo[(256 + j) * 64 + k] = f2bf(v - bf2f(h));
  } else if (t < 5120) {                 // g2: KTOT=256
    int l = t - 1024; int j = l >> 8, k = l & 255;
    float v = 0.f;
    if (j < 8) {
      int head = j & 3;
      const float* att = (j < 4 ? g2_as : g2_ad) + head * 64;
      for (int c = 0; c < 64; ++c) v += g2_w[(size_t)k * 256 + head * 64 + c] * att[c];
    }
    ushort h = f2bf(v);
    w2_hi[(256 + j) * 256 + k] = h;
    w2_lo[(256 + j) * 256 + k] = f2bf(v - bf2f(h));
  }
}

// ---------------- MFMA GEMM (BM=128, BN=64/block): 3-pass bf16 ----------------
// grid = dim3(n_colblocks, GB); col-block is the FAST dim (L2 A-reuse).
// OUTMODE 0: f32 out. OUTMODE 1: bias+relu, split hi/lo bf16. OUTMODE 2: bf16.
// LOGIT: last col-block additionally computes fragment at col 256 (16 cols)
// and scatters into a_s/a_d f32 [M][4].
template<int KTOT, int NFRAG, int OUTMODE, bool LOGIT>
__global__ __launch_bounds__(256) void mfma_gemm(
    const ushort* __restrict__ Ahi, const ushort* __restrict__ Alo,
    const ushort* __restrict__ Bhi, const ushort* __restrict__ Blo,
    const float* __restrict__ bias,
    float* __restrict__ outF, ushort* __restrict__ outHi, ushort* __restrict__ outLo,
    float* __restrict__ a_s, float* __restrict__ a_d,
    int M, int Ntot)
{
  __shared__ ushort AsH[128 * 64];
  __shared__ ushort AsL[128 * 64];
  const int tid  = threadIdx.x;
  const int lane = tid & 63;
  const int wid  = tid >> 6;
  const int row0 = blockIdx.y * 128;
  const int col0 = blockIdx.x * 64;
  const bool lastblk = LOGIT && ((int)blockIdx.x == (int)gridDim.x - 1);

  f32x4 acc[2][NFRAG];
  f32x4 accL[2];
#pragma unroll
  for (int m = 0; m < 2; ++m) {
#pragma unroll
    for (int n = 0; n < NFRAG; ++n) acc[m][n] = (f32x4){0.f, 0.f, 0.f, 0.f};
    accL[m] = (f32x4){0.f, 0.f, 0.f, 0.f};
  }

  const int rsub = lane >> 3;   // row within 8-row chunk
  const int slot = lane & 7;    // 16B slot within 128B LDS row
  const int brow = col0 + (lane & 15);
  const int bk   = (lane >> 4) * 8;

  for (int kt = 0; kt < KTOT; kt += 64) {
    // ---- stage A tile (hi+lo): 16 chunks of 8 rows x 128B, swizzled source ----
#pragma unroll
    for (int i = 0; i < 4; ++i) {
      const int c  = i * 4 + wid;
      const int r  = c * 8 + rsub;
      const int gr = min(row0 + r, M - 1);
      const int ss = slot ^ rsub;                       // involution swizzle (T2)
      const size_t goff = (size_t)gr * KTOT + kt + ss * 8;
      __builtin_amdgcn_global_load_lds(
          (const __attribute__((address_space(1))) void*)(Ahi + goff),
          (__attribute__((address_space(3))) void*)(AsH + c * 512), 16, 0, 0);
      __builtin_amdgcn_global_load_lds(
          (const __attribute__((address_space(1))) void*)(Alo + goff),
          (__attribute__((address_space(3))) void*)(AsL + c * 512), 16, 0, 0);
    }
    __syncthreads();

#pragma unroll
    for (int ks = 0; ks < 2; ++ks) {
      short8v ah[2], al[2], bh[NFRAG], bl[NFRAG];
#pragma unroll
      for (int mf = 0; mf < 2; ++mf) {
        const int r   = wid * 32 + mf * 16 + (lane & 15);
        const int sl  = (ks * 4 + (lane >> 4)) ^ (r & 7);
        const int idx = r * 64 + sl * 8;
        ah[mf] = *(const short8v*)(AsH + idx);
        al[mf] = *(const short8v*)(AsL + idx);
      }
#pragma unroll
      for (int nf = 0; nf < NFRAG; ++nf) {
        const size_t bo = (size_t)(brow + nf * 16) * KTOT + kt + ks * 32 + bk;
        bh[nf] = *(const short8v*)(Bhi + bo);
        bl[nf] = *(const short8v*)(Blo + bo);
      }
#pragma unroll
      for (int mf = 0; mf < 2; ++mf)
#pragma unroll
        for (int nf = 0; nf < NFRAG; ++nf) {
          acc[mf][nf] = __builtin_amdgcn_mfma_f32_16x16x32_bf16(ah[mf], bh[nf], acc[mf][nf], 0, 0, 0);
          acc[mf][nf] = __builtin_amdgcn_mfma_f32_16x16x32_bf16(al[mf], bh[nf], acc[mf][nf], 0, 0, 0);
          acc[mf][nf] = __builtin_amdgcn_mfma_f32_16x16x32_bf16(ah[mf], bl[nf], acc[mf][nf], 0, 0, 0);
        }
      if (lastblk) {   // fused logits fragment (cols 256..271 of Bcat)
        const size_t bo = (size_t)(256 + (lane & 15)) * KTOT + kt + ks * 32 + bk;
        const short8v bhl = *(const short8v*)(Bhi + bo);
        const short8v bll = *(const short8v*)(Blo + bo);
#pragma unroll
        for (int mf = 0; mf < 2; ++mf) {
          accL[mf] = __builtin_amdgcn_mfma_f32_16x16x32_bf16(ah[mf], bhl, accL[mf], 0, 0, 0);
          accL[mf] = __builtin_amdgcn_mfma_f32_16x16x32_bf16(al[mf], bhl, accL[mf], 0, 0, 0);
          accL[mf] = __builtin_amdgcn_mfma_f32_16x16x32_bf16(ah[mf], bll, accL[mf], 0, 0, 0);
        }
      }
    }
    __syncthreads();
  }

  // ---- epilogue: C/D frag layout col=lane&15, row=(lane>>4)*4+reg ----
  const int crow = row0 + wid * 32 + (lane >> 4) * 4;
  const int ccol = col0 + (lane & 15);
#pragma unroll
  for (int mf = 0; mf < 2; ++mf)
#pragma unroll
    for (int nf = 0; nf < NFRAG; ++nf)
#pragma unroll
      for (int r = 0; r < 4; ++r) {
        const int grow = crow + mf * 16 + r;
        const int gcol = ccol + nf * 16;
        if (grow >= M) continue;
        float v = acc[mf][nf][r];
        if (OUTMODE == 0) {
          outF[(size_t)grow * Ntot + gcol] = v;
        } else if (OUTMODE == 1) {
          v = fmaxf(v + bias[gcol], 0.f);
          const ushort h = f2bf(v);
          outHi[(size_t)grow * Ntot + gcol] = h;
          outLo[(size_t)grow * Ntot + gcol] = f2bf(v - bf2f(h));
        } else {
          outHi[(size_t)grow * FDIM + gcol] = f2bf(v);
        }
      }
  if (lastblk) {
    const int c8 = lane & 15;
#pragma unroll
    for (int mf = 0; mf < 2; ++mf)
#pragma unroll
      for (int r = 0; r < 4; ++r) {
        const int grow = crow + mf * 16 + r;
        if (grow >= M) continue;
        const float v = accL[mf][r];
        if (c8 < 4)      a_s[grow * 4 + c8] = v;
        else if (c8 < 8) a_d[grow * 4 + (c8 - 4)] = v;
      }
  }
}

// ---------------- CSR build ----------------
__global__ void hist_kernel(const int* __restrict__ dst, int* __restrict__ deg, int E)
{
  int i = blockIdx.x * blockDim.x + threadIdx.x;
  if (i < E) atomicAdd(&deg[dst[i]], 1);
}

__global__ void scan1_kernel(const int* __restrict__ deg, int* __restrict__ off,
                             int* __restrict__ bsum, int n)
{
  __shared__ int ws[4];
  const int t = threadIdx.x, lane = t & 63, w = t >> 6;
  const int i = blockIdx.x * 256 + t;
  const int v = (i < n) ? deg[i] : 0;
  int x = v;
#pragma unroll
  for (int d = 1; d < 64; d <<= 1) {
    int y = __shfl_up(x, d, 64);
    if (lane >= d) x += y;
  }
  if (lane == 63) ws[w] = x;
  __syncthreads();
  int add = 0;
  for (int k = 0; k < w; ++k) add += ws[k];
  if (i < n) off[i] = add + x - v;
  if (t == 255) bsum[blockIdx.x] = add + x;
}

__global__ void scan2_kernel(int* __restrict__ bsum, int nb)
{
  __shared__ int ws[4];
  const int t = threadIdx.x, lane = t & 63, w = t >> 6;
  const int v = (t < nb) ? bsum[t] : 0;
  int x = v;
#pragma unroll
  for (int d = 1; d < 64; d <<= 1) {
    int y = __shfl_up(x, d, 64);
    if (lane >= d) x += y;
  }
  if (lane == 63) ws[w] = x;
  __syncthreads();
  int add = 0;
  for (int k = 0; k < w; ++k) add += ws[k];
  if (t < nb) bsum[t] = add + x - v;
}

__global__ void scan3_kernel(int* __restrict__ off, const int* __restrict__ bsum, int n, int E)
{
  const int i = blockIdx.x * 256 + threadIdx.x;
  if (i < n) off[i] += bsum[blockIdx.x];
  if (i == 0) off[n] = E;
}

__global__ void scatter_kernel(const int* __restrict__ src, const int* __restrict__ dst,
                               const int* __restrict__ off, int* __restrict__ cursor,
                               int* __restrict__ sidx, int E)
{
  int i = blockIdx.x * blockDim.x + threadIdx.x;
  if (i < E) {
    int d = dst[i];
    int p = atomicAdd(&cursor[d], 1);
    sidx[off[d] + p] = src[i];
  }
}

// ---------------- GAT aggregation v5: one wave per dst node ----------------
// Phase A: online (m,s) per head (each (edge,head) touched by exactly one lane).
// Phase B: per 16-edge chunk, 64 lanes compute the 16x4 softmax weights ONCE
// into LDS (lane already holds its head's converged max), then the gather loop
// reads weights by LDS broadcast -> 16x less exp/lrelu VALU.
__global__ __launch_bounds__(256) void aggregate_kernel(
    const ushort* __restrict__ hWb, const int* __restrict__ sidx,
    const int* __restrict__ off, const float* __restrict__ a_s, const float* __restrict__ a_d,
    const float* __restrict__ bias,
    ushort* __restrict__ outHi, ushort* __restrict__ outLo, int n_nodes)
{
  __shared__ float wlds[4][16][4];
  const int w    = threadIdx.x >> 6;
  const int wid  = (blockIdx.x * 256 + threadIdx.x) >> 6;
  const int lane = threadIdx.x & 63;
  if (wid >= n_nodes) return;
  const int n = wid;
  const int beg = off[n], end = off[n + 1];

  // ---- Phase A ----
  const int es   = lane >> 2;    // edge slot 0..15
  const int hh   = lane & 3;     // head
  const float adh = a_d[(unsigned)n * 4 + hh];
  float m = -1e30f, ssum = 0.f;
  for (int j = beg + es; j < end; j += 16) {
    const unsigned s = (unsigned)sidx[j];
    const float e = lrelu(a_s[s * 4 + hh] + adh);
    const float mn = fmaxf(m, e);
    ssum = ssum * __expf(m - mn) + __expf(e - mn);
    m = mn;
  }
#pragma unroll
  for (int d = 4; d < 64; d <<= 1) {
    const float mo = __shfl_xor(m, d, 64);
    const float so = __shfl_xor(ssum, d, 64);
    const float mn = fmaxf(m, mo);
    ssum = ssum * __expf(m - mn) + so * __expf(mo - mn);
    m = mn;
  }
  // every lane now holds (m, ssum) for its head class hh
  const int hb = lane >> 4;                    // head this lane accumulates in B
  const float sh = __shfl(ssum, hb, 64);       // lane hb holds head hb

  // ---- Phase B: chunked, weights via LDS ----
  float acc0 = 0.f, acc1 = 0.f, acc2 = 0.f, acc3 = 0.f;
  const unsigned lo4 = (unsigned)(lane << 2);
  for (int j0 = beg; j0 < end; j0 += 16) {
    const int jj = j0 + es;
    float wv = 0.f;
    if (jj < end) {
      const unsigned s = (unsigned)sidx[jj];
      const float e = lrelu(a_s[s * 4 + hh] + adh);
      wv = __expf(e - m);                      // m = this lane's head max
    }
    wlds[w][es][hh] = wv;
    const int jend = min(j0 + 16, end);
#pragma unroll 4
    for (int j = j0; j < jend; ++j) {
      const unsigned s = (unsigned)sidx[j];
      const float wgt = wlds[w][j - j0][hb];
      const ushort4 hv = *(const ushort4*)(hWb + s * (unsigned)FDIM + lo4);
      acc0 = fmaf(wgt, bf2f(hv.x), acc0);
      acc1 = fmaf(wgt, bf2f(hv.y), acc1);
      acc2 = fmaf(wgt, bf2f(hv.z), acc2);
      acc3 = fmaf(wgt, bf2f(hv.w), acc3);
    }
  }
  const float inv = 1.f / (sh + 1e-16f);
  const float4 bv = *(const float4*)(bias + lo4);
  const float v0 = acc0 * inv + bv.x;
  const float v1 = acc1 * inv + bv.y;
  const float v2 = acc2 * inv + bv.z;
  const float v3 = acc3 * inv + bv.w;
  const ushort h0 = f2bf(v0), h1 = f2bf(v1), h2 = f2bf(v2), h3 = f2bf(v3);
  *(ushort4*)(outHi + (unsigned)n * FDIM + lo4) = make_ushort4(h0, h1, h2, h3);
  *(ushort4*)(outLo + (unsigned)n * FDIM + lo4) = make_ushort4(
      f2bf(v0 - bf2f(h0)), f2bf(v1 - bf2f(h1)),
      f2bf(v2 - bf2f(h2)), f2bf(v3 - bf2f(h3)));
}

// ---------------- link predictor: 16 pairs/block, 4 per wave ----------------
__global__ __launch_bounds__(256) void linkpred_kernel(
    const float* __restrict__ uv,
    const int* __restrict__ es, const int* __restrict__ ed,
    const float* __restrict__ b1, const float* __restrict__ w2, const float* __restrict__ b2,
    const float* __restrict__ w3, const float* __restrict__ b3,
    float* __restrict__ out, int n_eval)
{
  __shared__ float w2s[64 * 32];
  __shared__ float z1s[4][4][64];
  const int t = threadIdx.x;
  for (int i = t; i < 64 * 32; i += 256) w2s[i] = w2[i];
  const int w = t >> 6, lane = t & 63;
  const int pair0 = blockIdx.x * 16 + w * 4;
#pragma unroll
  for (int p = 0; p < 4; ++p) {
    const int pc = min(pair0 + p, n_eval - 1);
    const int s = es[pc], d = ed[pc];
    z1s[w][p][lane] = fmaxf(uv[(unsigned)s * 128 + lane] + uv[(unsigned)d * 128 + 64 + lane] + b1[lane], 0.f);
  }
  __syncthreads();
  const int half = lane >> 5;
  const int col  = lane & 31;
  const float w3c = w3[col];
#pragma unroll
  for (int pp = 0; pp < 2; ++pp) {
    const int p = pp * 2 + half;
    float acc = b2[col];
#pragma unroll
    for (int k = 0; k < 64; ++k) acc = fmaf(z1s[w][p][k], w2s[k * 32 + col], acc);
    float zz = fmaxf(acc, 0.f) * w3c;
#pragma unroll
    for (int d = 1; d < 32; d <<= 1) zz += __shfl_xor(zz, d, 64);
    if (col == 0) {
      const int pv = pair0 + p;
      if (pv < n_eval) out[pv] = zz + b3[0];
    }
  }
}

// ---------------- launch ----------------
extern "C" void kernel_launch(void* const* d_in, const int* in_sizes, int n_in,
                              void* d_out, int out_size, void* d_ws, size_t ws_size,
                              hipStream_t stream)
{
  const float* x     = (const float*)d_in[0];
  const int*   ei    = (const int*)d_in[1];
  const int*   esrc  = (const int*)d_in[2];
  const int*   edst  = (const int*)d_in[3];
  const float* enc_w = (const float*)d_in[4];
  const float* enc_b = (const float*)d_in[5];
  const float* g1_w  = (const float*)d_in[6];
  const float* g1_as = (const float*)d_in[7];
  const float* g1_ad = (const float*)d_in[8];
  const float* g1_b  = (const float*)d_in[9];
  const float* g2_w  = (const float*)d_in[10];
  const float* g2_as = (const float*)d_in[11];
  const float* g2_ad = (const float*)d_in[12];
  const float* g2_b  = (const float*)d_in[13];
  const float* lp1_w = (const float*)d_in[14];
  const float* lp1_b = (const float*)d_in[15];
  const float* lp2_w = (const float*)d_in[16];
  const float* lp2_b = (const float*)d_in[17];
  const float* lp3_w = (const float*)d_in[18];
  const float* lp3_b = (const float*)d_in[19];
  float* out = (float*)d_out;

  const int E  = in_sizes[1] / 2;   // 1,000,000
  const int NE = in_sizes[2];       // 100,000
  const int M  = NNODES;
  const int NB = (M + 255) / 256;   // scan blocks

  const int* e_src = ei;
  const int* e_dst = ei + E;

  // ---- workspace layout ----
  ushort* hWb  = (ushort*)d_ws;                        // M*256 bf16 (aliased by uv later)
  float* a_s   = (float*)(hWb + (size_t)M * FDIM);     // M*4
  float* a_d   = a_s + (size_t)M * HEADS;              // M*4
  ushort* h_hi = (ushort*)(a_d + (size_t)M * HEADS);   // M*64
  ushort* h_lo = h_hi + (size_t)M * HID;
  ushort* agg_hi = h_lo + (size_t)M * HID;             // M*256 (also x_hi)
  ushort* agg_lo = agg_hi + (size_t)M * FDIM;          // (also x_lo)
  int*   deg    = (int*)(agg_lo + (size_t)M * FDIM);
  int*   cursor = deg + M;
  int*   off    = cursor + M;
  int*   bsum   = off + M + 1;                         // 256 ints
  int*   sidx   = bsum + 256;
  ushort* wb     = (ushort*)(sidx + E);
  ushort* we_hi  = wb;                  ushort* we_lo  = we_hi + 64 * 256;
  ushort* w1_hi  = we_lo + 64 * 256;    ushort* w1_lo  = w1_hi + 272 * 64;
  ushort* w2_hi  = w1_lo + 272 * 64;    ushort* w2_lo  = w2_hi + 272 * 256;
  ushort* wlp_hi = w2_lo + 272 * 256;   ushort* wlp_lo = wlp_hi + 128 * 256;
  ushort* x_hi = agg_hi;   // x planes dead after encoder
  ushort* x_lo = agg_lo;
  float* uv = (float*)hWb; // hWb dead after aggregate2; uv = M*128 f32

  // ---- CSR build ----
  hipMemsetAsync(deg, 0, sizeof(int) * 2 * (size_t)M, stream);
  hist_kernel<<<(E + 255) / 256, 256, 0, stream>>>(e_dst, deg, E);
  scan1_kernel<<<NB, 256, 0, stream>>>(deg, off, bsum, M);
  scan2_kernel<<<1, 256, 0, stream>>>(bsum, NB);
  scan3_kernel<<<NB, 256, 0, stream>>>(off, bsum, M, E);
  scatter_kernel<<<(E + 255) / 256, 256, 0, stream>>>(e_src, e_dst, off, cursor, sidx, E);

  // ---- conversions ----
  {
    int n4 = M * FDIM / 4;
    split_kernel<<<(n4 + 255) / 256, 256, 0, stream>>>((const float4*)x, x_hi, x_lo, n4);
    wtconv_all_kernel<<<512, 256, 0, stream>>>(enc_w, g1_w, g2_w, lp1_w,
                                               we_hi, we_lo, w1_hi, w1_lo,
                                               w2_hi, w2_lo, wlp_hi, wlp_lo);
    attcomb_kernel<<<20, 256, 0, stream>>>(g1_w, g1_as, g1_ad, g2_w, g2_as, g2_ad,
                                           w1_hi, w1_lo, w2_hi, w2_lo);
  }

  const int GB = (M + 127) / 128;   // 391 row-blocks

  // ---- encoder: h = relu(x @ enc_w + b) ----
  mfma_gemm<256, 4, 1, false><<<dim3(1, GB), 256, 0, stream>>>(
      x_hi, x_lo, we_hi, we_lo, enc_b, nullptr, h_hi, h_lo, nullptr, nullptr, M, HID);

  // ---- GAT layer 1: one GEMM launch (cols 0..255 + fused logits on last block) ----
  mfma_gemm<64, 4, 2, true><<<dim3(4, GB), 256, 0, stream>>>(
      h_hi, h_lo, w1_hi, w1_lo, nullptr, nullptr, hWb, nullptr, a_s, a_d, M, FDIM);
  aggregate_kernel<<<(M * 64 + 255) / 256, 256, 0, stream>>>(
      hWb, sidx, off, a_s, a_d, g1_b, agg_hi, agg_lo, M);

  // ---- GAT layer 2 ----
  mfma_gemm<256, 4, 2, true><<<dim3(4, GB), 256, 0, stream>>>(
      agg_hi, agg_lo, w2_hi, w2_lo, nullptr, nullptr, hWb, nullptr, a_s, a_d, M, FDIM);
  aggregate_kernel<<<(M * 64 + 255) / 256, 256, 0, stream>>>(
      hWb, sidx, off, a_s, a_d, g2_b, agg_hi, agg_lo, M);

  // ---- link predictor ----
  mfma_gemm<256, 4, 0, false><<<dim3(2, GB), 256, 0, stream>>>(
      agg_hi, agg_lo, wlp_hi, wlp_lo, nullptr, uv, nullptr, nullptr, nullptr, nullptr, M, 2 * HID);
  linkpred_kernel<<<(NE + 15) / 16, 256, 0, stream>>>(uv, esrc, edst, lp1_b, lp2_w, lp2_b,
                                                      lp3_w, lp3_b, out, NE);
}

// Round 9
// 534.730 us; speedup vs baseline: 1.1623x; 1.1623x over previous
//
#include <hip/hip_runtime.h>
#include <hip/hip_bf16.h>
#include <math.h>

#define NNODES 50000
#define HID    64
#define HEADS  4
#define FDIM   256   // HEADS*HID

typedef __attribute__((ext_vector_type(8))) _Float16 half8v;
typedef __attribute__((ext_vector_type(4))) _Float16 half4v;
typedef __attribute__((ext_vector_type(4))) float f32x4;

__device__ __forceinline__ float lrelu(float x) { return fmaxf(x, 0.2f * x); }

// ---------------- f32 -> f16 convert, vectorized ----------------
__global__ void split_kernel(const float4* __restrict__ x, _Float16* __restrict__ xh, int n4)
{
  int t = blockIdx.x * blockDim.x + threadIdx.x;
  if (t >= n4) return;
  float4 v = x[t];
  half4v o = {(_Float16)v.x, (_Float16)v.y, (_Float16)v.z, (_Float16)v.w};
  *(half4v*)(xh + (size_t)t * 4) = o;
}

// ---------------- weight transposes (rows 0..255 of cat arrays), f16 ----------------
__global__ void wtconv_all_kernel(const float* __restrict__ enc_w, const float* __restrict__ g1_w,
                                  const float* __restrict__ g2_w, const float* __restrict__ lp1_w,
                                  _Float16* __restrict__ we, _Float16* __restrict__ w1,
                                  _Float16* __restrict__ w2, _Float16* __restrict__ wlp)
{
  int t = blockIdx.x * blockDim.x + threadIdx.x;   // 0..131071
  float w; _Float16* dh; int di;
  if (t < 16384) {                       // enc: N=64,K=256
    int n = t >> 8, k = t & 255;
    w = enc_w[(size_t)k * 64 + n]; dh = we; di = t;
  } else if (t < 32768) {                // g1: N=256,K=64
    int l = t - 16384; int n = l >> 6, k = l & 63;
    w = g1_w[(size_t)k * 256 + n]; dh = w1; di = l;
  } else if (t < 98304) {                // g2: N=256,K=256
    int l = t - 32768; int n = l >> 8, k = l & 255;
    w = g2_w[(size_t)k * 256 + n]; dh = w2; di = l;
  } else {                               // lp stacked: N=128,K=256
    int l = t - 98304; int n = l >> 8, k = l & 255;
    int srow = (n < 64) ? k : (256 + k);
    w = lp1_w[(size_t)srow * 64 + (n & 63)]; dh = wlp; di = l;
  }
  dh[di] = (_Float16)w;
}

// ---------------- att-combined columns: rows 256..271 of w1cat/w2cat ----------------
__global__ void attcomb_kernel(const float* __restrict__ g1_w, const float* __restrict__ g1_as,
                               const float* __restrict__ g1_ad,
                               const float* __restrict__ g2_w, const float* __restrict__ g2_as,
                               const float* __restrict__ g2_ad,
                               _Float16* __restrict__ w1, _Float16* __restrict__ w2)
{
  int t = blockIdx.x * blockDim.x + threadIdx.x;   // 0..5119
  if (t < 1024) {                        // g1: KTOT=64
    int j = t >> 6, k = t & 63;
    float v = 0.f;
    if (j < 8) {
      int head = j & 3;
      const float* att = (j < 4 ? g1_as : g1_ad) + head * 64;
      for (int c = 0; c < 64; ++c) v += g1_w[(size_t)k * 256 + head * 64 + c] * att[c];
    }
    w1[(256 + j) * 64 + k] = (_Float16)v;
  } else if (t < 5120) {                 // g2: KTOT=256
    int l = t - 1024; int j = l >> 8, k = l & 255;
    float v = 0.f;
    if (j < 8) {
      int head = j & 3;
      const float* att = (j < 4 ? g2_as : g2_ad) + head * 64;
      for (int c = 0; c < 64; ++c) v += g2_w[(size_t)k * 256 + head * 64 + c] * att[c];
    }
    w2[(256 + j) * 256 + k] = (_Float16)v;
  }
}

// ---------------- MFMA GEMM (BM=128, BN=64/block): single-pass f16 ----------------
// grid = dim3(n_colblocks, GB); col-block is the FAST dim (L2 A-reuse).
// OUTMODE 0: f32 out. OUTMODE 1: bias+relu, f16 out. OUTMODE 2: f16 out.
// LOGIT: last col-block also computes cols 256..271 -> a_s/a_d f32 [M][4].
template<int KTOT, int NFRAG, int OUTMODE, bool LOGIT>
__global__ __launch_bounds__(256) void mfma_gemm(
    const _Float16* __restrict__ A, const _Float16* __restrict__ B,
    const float* __restrict__ bias,
    float* __restrict__ outF, _Float16* __restrict__ outH,
    float* __restrict__ a_s, float* __restrict__ a_d,
    int M, int Ntot)
{
  __shared__ _Float16 As[128 * 64];
  const int tid  = threadIdx.x;
  const int lane = tid & 63;
  const int wid  = tid >> 6;
  const int row0 = blockIdx.y * 128;
  const int col0 = blockIdx.x * 64;
  const bool lastblk = LOGIT && ((int)blockIdx.x == (int)gridDim.x - 1);

  f32x4 acc[2][NFRAG];
  f32x4 accL[2];
#pragma unroll
  for (int m = 0; m < 2; ++m) {
#pragma unroll
    for (int n = 0; n < NFRAG; ++n) acc[m][n] = (f32x4){0.f, 0.f, 0.f, 0.f};
    accL[m] = (f32x4){0.f, 0.f, 0.f, 0.f};
  }

  const int rsub = lane >> 3;   // row within 8-row chunk
  const int slot = lane & 7;    // 16B slot within 128B LDS row
  const int brow = col0 + (lane & 15);
  const int bk   = (lane >> 4) * 8;

  for (int kt = 0; kt < KTOT; kt += 64) {
    // ---- stage A tile: 16 chunks of 8 rows x 128B, swizzled source ----
#pragma unroll
    for (int i = 0; i < 4; ++i) {
      const int c  = i * 4 + wid;
      const int r  = c * 8 + rsub;
      const int gr = min(row0 + r, M - 1);
      const int ss = slot ^ rsub;                       // involution swizzle (T2)
      const size_t goff = (size_t)gr * KTOT + kt + ss * 8;
      __builtin_amdgcn_global_load_lds(
          (const __attribute__((address_space(1))) void*)(A + goff),
          (__attribute__((address_space(3))) void*)(As + c * 512), 16, 0, 0);
    }
    __syncthreads();

#pragma unroll
    for (int ks = 0; ks < 2; ++ks) {
      half8v ah[2], bh[NFRAG];
#pragma unroll
      for (int mf = 0; mf < 2; ++mf) {
        const int r   = wid * 32 + mf * 16 + (lane & 15);
        const int sl  = (ks * 4 + (lane >> 4)) ^ (r & 7);
        ah[mf] = *(const half8v*)(As + r * 64 + sl * 8);
      }
#pragma unroll
      for (int nf = 0; nf < NFRAG; ++nf) {
        const size_t bo = (size_t)(brow + nf * 16) * KTOT + kt + ks * 32 + bk;
        bh[nf] = *(const half8v*)(B + bo);
      }
#pragma unroll
      for (int mf = 0; mf < 2; ++mf)
#pragma unroll
        for (int nf = 0; nf < NFRAG; ++nf)
          acc[mf][nf] = __builtin_amdgcn_mfma_f32_16x16x32_f16(ah[mf], bh[nf], acc[mf][nf], 0, 0, 0);
      if (lastblk) {   // fused logits fragment (cols 256..271 of Bcat)
        const size_t bo = (size_t)(256 + (lane & 15)) * KTOT + kt + ks * 32 + bk;
        const half8v bhl = *(const half8v*)(B + bo);
#pragma unroll
        for (int mf = 0; mf < 2; ++mf)
          accL[mf] = __builtin_amdgcn_mfma_f32_16x16x32_f16(ah[mf], bhl, accL[mf], 0, 0, 0);
      }
    }
    __syncthreads();
  }

  // ---- epilogue: C/D frag layout col=lane&15, row=(lane>>4)*4+reg ----
  const int crow = row0 + wid * 32 + (lane >> 4) * 4;
  const int ccol = col0 + (lane & 15);
#pragma unroll
  for (int mf = 0; mf < 2; ++mf)
#pragma unroll
    for (int nf = 0; nf < NFRAG; ++nf)
#pragma unroll
      for (int r = 0; r < 4; ++r) {
        const int grow = crow + mf * 16 + r;
        const int gcol = ccol + nf * 16;
        if (grow >= M) continue;
        float v = acc[mf][nf][r];
        if (OUTMODE == 0) {
          outF[(size_t)grow * Ntot + gcol] = v;
        } else if (OUTMODE == 1) {
          v = fmaxf(v + bias[gcol], 0.f);
          outH[(size_t)grow * Ntot + gcol] = (_Float16)v;
        } else {
          outH[(size_t)grow * FDIM + gcol] = (_Float16)v;
        }
      }
  if (lastblk) {
    const int c8 = lane & 15;
#pragma unroll
    for (int mf = 0; mf < 2; ++mf)
#pragma unroll
      for (int r = 0; r < 4; ++r) {
        const int grow = crow + mf * 16 + r;
        if (grow >= M) continue;
        const float v = accL[mf][r];
        if (c8 < 4)      a_s[grow * 4 + c8] = v;
        else if (c8 < 8) a_d[grow * 4 + (c8 - 4)] = v;
      }
  }
}

// ---------------- CSR build ----------------
__global__ void hist_kernel(const int* __restrict__ dst, int* __restrict__ deg, int E)
{
  int i = blockIdx.x * blockDim.x + threadIdx.x;
  if (i < E) atomicAdd(&deg[dst[i]], 1);
}

__global__ void scan1_kernel(const int* __restrict__ deg, int* __restrict__ off,
                             int* __restrict__ bsum, int n)
{
  __shared__ int ws[4];
  const int t = threadIdx.x, lane = t & 63, w = t >> 6;
  const int i = blockIdx.x * 256 + t;
  const int v = (i < n) ? deg[i] : 0;
  int x = v;
#pragma unroll
  for (int d = 1; d < 64; d <<= 1) {
    int y = __shfl_up(x, d, 64);
    if (lane >= d) x += y;
  }
  if (lane == 63) ws[w] = x;
  __syncthreads();
  int add = 0;
  for (int k = 0; k < w; ++k) add += ws[k];
  if (i < n) off[i] = add + x - v;
  if (t == 255) bsum[blockIdx.x] = add + x;
}

__global__ void scan2_kernel(int* __restrict__ bsum, int nb)
{
  __shared__ int ws[4];
  const int t = threadIdx.x, lane = t & 63, w = t >> 6;
  const int v = (t < nb) ? bsum[t] : 0;
  int x = v;
#pragma unroll
  for (int d = 1; d < 64; d <<= 1) {
    int y = __shfl_up(x, d, 64);
    if (lane >= d) x += y;
  }
  if (lane == 63) ws[w] = x;
  __syncthreads();
  int add = 0;
  for (int k = 0; k < w; ++k) add += ws[k];
  if (t < nb) bsum[t] = add + x - v;
}

__global__ void scan3_kernel(int* __restrict__ off, const int* __restrict__ bsum, int n, int E)
{
  const int i = blockIdx.x * 256 + threadIdx.x;
  if (i < n) off[i] += bsum[blockIdx.x];
  if (i == 0) off[n] = E;
}

__global__ void scatter_kernel(const int* __restrict__ src, const int* __restrict__ dst,
                               const int* __restrict__ off, int* __restrict__ cursor,
                               int* __restrict__ sidx, int E)
{
  int i = blockIdx.x * blockDim.x + threadIdx.x;
  if (i < E) {
    int d = dst[i];
    int p = atomicAdd(&cursor[d], 1);
    sidx[off[d] + p] = src[i];
  }
}

// ---------------- GAT aggregation: one wave per dst node (f16 messages) ----------------
__global__ __launch_bounds__(256) void aggregate_kernel(
    const _Float16* __restrict__ hW, const int* __restrict__ sidx,
    const int* __restrict__ off, const float* __restrict__ a_s, const float* __restrict__ a_d,
    const float* __restrict__ bias,
    _Float16* __restrict__ outH, int n_nodes)
{
  __shared__ float wlds[4][16][4];
  const int w    = threadIdx.x >> 6;
  const int wid  = (blockIdx.x * 256 + threadIdx.x) >> 6;
  const int lane = threadIdx.x & 63;
  if (wid >= n_nodes) return;
  const int n = wid;
  const int beg = off[n], end = off[n + 1];

  // ---- Phase A: online (m, s) per head ----
  const int es   = lane >> 2;    // edge slot 0..15
  const int hh   = lane & 3;     // head
  const float adh = a_d[(unsigned)n * 4 + hh];
  float m = -1e30f, ssum = 0.f;
  for (int j = beg + es; j < end; j += 16) {
    const unsigned s = (unsigned)sidx[j];
    const float e = lrelu(a_s[s * 4 + hh] + adh);
    const float mn = fmaxf(m, e);
    ssum = ssum * __expf(m - mn) + __expf(e - mn);
    m = mn;
  }
#pragma unroll
  for (int d = 4; d < 64; d <<= 1) {
    const float mo = __shfl_xor(m, d, 64);
    const float so = __shfl_xor(ssum, d, 64);
    const float mn = fmaxf(m, mo);
    ssum = ssum * __expf(m - mn) + so * __expf(mo - mn);
    m = mn;
  }
  const int hb = lane >> 4;                    // head this lane accumulates in B
  const float sh = __shfl(ssum, hb, 64);

  // ---- Phase B: chunked, weights via LDS broadcast ----
  float acc0 = 0.f, acc1 = 0.f, acc2 = 0.f, acc3 = 0.f;
  const unsigned lo4 = (unsigned)(lane << 2);
  for (int j0 = beg; j0 < end; j0 += 16) {
    const int jj = j0 + es;
    float wv = 0.f;
    if (jj < end) {
      const unsigned s = (unsigned)sidx[jj];
      const float e = lrelu(a_s[s * 4 + hh] + adh);
      wv = __expf(e - m);
    }
    wlds[w][es][hh] = wv;
    const int jend = min(j0 + 16, end);
#pragma unroll 4
    for (int j = j0; j < jend; ++j) {
      const unsigned s = (unsigned)sidx[j];
      const float wgt = wlds[w][j - j0][hb];
      const half4v hv = *(const half4v*)(hW + s * (unsigned)FDIM + lo4);
      acc0 = fmaf(wgt, (float)hv.x, acc0);
      acc1 = fmaf(wgt, (float)hv.y, acc1);
      acc2 = fmaf(wgt, (float)hv.z, acc2);
      acc3 = fmaf(wgt, (float)hv.w, acc3);
    }
  }
  const float inv = 1.f / (sh + 1e-16f);
  const float4 bv = *(const float4*)(bias + lo4);
  half4v o = {(_Float16)(acc0 * inv + bv.x), (_Float16)(acc1 * inv + bv.y),
              (_Float16)(acc2 * inv + bv.z), (_Float16)(acc3 * inv + bv.w)};
  *(half4v*)(outH + (unsigned)n * FDIM + lo4) = o;
}

// ---------------- link predictor: 16 pairs/block, 4 per wave ----------------
__global__ __launch_bounds__(256) void linkpred_kernel(
    const float* __restrict__ uv,
    const int* __restrict__ es, const int* __restrict__ ed,
    const float* __restrict__ b1, const float* __restrict__ w2, const float* __restrict__ b2,
    const float* __restrict__ w3, const float* __restrict__ b3,
    float* __restrict__ out, int n_eval)
{
  __shared__ float w2s[64 * 32];
  __shared__ float z1s[4][4][64];
  const int t = threadIdx.x;
  for (int i = t; i < 64 * 32; i += 256) w2s[i] = w2[i];
  const int w = t >> 6, lane = t & 63;
  const int pair0 = blockIdx.x * 16 + w * 4;
#pragma unroll
  for (int p = 0; p < 4; ++p) {
    const int pc = min(pair0 + p, n_eval - 1);
    const int s = es[pc], d = ed[pc];
    z1s[w][p][lane] = fmaxf(uv[(unsigned)s * 128 + lane] + uv[(unsigned)d * 128 + 64 + lane] + b1[lane], 0.f);
  }
  __syncthreads();
  const int half = lane >> 5;
  const int col  = lane & 31;
  const float w3c = w3[col];
#pragma unroll
  for (int pp = 0; pp < 2; ++pp) {
    const int p = pp * 2 + half;
    float acc = b2[col];
#pragma unroll
    for (int k = 0; k < 64; ++k) acc = fmaf(z1s[w][p][k], w2s[k * 32 + col], acc);
    float zz = fmaxf(acc, 0.f) * w3c;
#pragma unroll
    for (int d = 1; d < 32; d <<= 1) zz += __shfl_xor(zz, d, 64);
    if (col == 0) {
      const int pv = pair0 + p;
      if (pv < n_eval) out[pv] = zz + b3[0];
    }
  }
}

// ---------------- launch ----------------
extern "C" void kernel_launch(void* const* d_in, const int* in_sizes, int n_in,
                              void* d_out, int out_size, void* d_ws, size_t ws_size,
                              hipStream_t stream)
{
  const float* x     = (const float*)d_in[0];
  const int*   ei    = (const int*)d_in[1];
  const int*   esrc  = (const int*)d_in[2];
  const int*   edst  = (const int*)d_in[3];
  const float* enc_w = (const float*)d_in[4];
  const float* enc_b = (const float*)d_in[5];
  const float* g1_w  = (const float*)d_in[6];
  const float* g1_as = (const float*)d_in[7];
  const float* g1_ad = (const float*)d_in[8];
  const float* g1_b  = (const float*)d_in[9];
  const float* g2_w  = (const float*)d_in[10];
  const float* g2_as = (const float*)d_in[11];
  const float* g2_ad = (const float*)d_in[12];
  const float* g2_b  = (const float*)d_in[13];
  const float* lp1_w = (const float*)d_in[14];
  const float* lp1_b = (const float*)d_in[15];
  const float* lp2_w = (const float*)d_in[16];
  const float* lp2_b = (const float*)d_in[17];
  const float* lp3_w = (const float*)d_in[18];
  const float* lp3_b = (const float*)d_in[19];
  float* out = (float*)d_out;

  const int E  = in_sizes[1] / 2;   // 1,000,000
  const int NE = in_sizes[2];       // 100,000
  const int M  = NNODES;
  const int NB = (M + 255) / 256;   // scan blocks

  const int* e_src = ei;
  const int* e_dst = ei + E;

  // ---- workspace layout ----
  _Float16* hWh = (_Float16*)d_ws;                     // M*256 f16 (alias uv f32 M*128)
  float* a_s   = (float*)(hWh + (size_t)M * FDIM);     // M*4
  float* a_d   = a_s + (size_t)M * HEADS;              // M*4
  _Float16* hh = (_Float16*)(a_d + (size_t)M * HEADS); // M*64
  _Float16* agg = hh + (size_t)M * HID;                // M*256 (also x_h)
  int*   deg    = (int*)(agg + (size_t)M * FDIM);
  int*   cursor = deg + M;
  int*   off    = cursor + M;
  int*   bsum   = off + M + 1;                         // 256 ints
  int*   sidx   = bsum + 256;
  _Float16* we  = (_Float16*)(sidx + E);               // 64*256
  _Float16* w1  = we + 64 * 256;                       // 272*64
  _Float16* w2  = w1 + 272 * 64;                       // 272*256
  _Float16* wlp = w2 + 272 * 256;                      // 128*256
  _Float16* x_h = agg;     // x plane dead after encoder; agg written later
  float* uv = (float*)hWh; // hWh dead after aggregate2; uv = M*128 f32

  // ---- CSR build ----
  hipMemsetAsync(deg, 0, sizeof(int) * 2 * (size_t)M, stream);
  hist_kernel<<<(E + 255) / 256, 256, 0, stream>>>(e_dst, deg, E);
  scan1_kernel<<<NB, 256, 0, stream>>>(deg, off, bsum, M);
  scan2_kernel<<<1, 256, 0, stream>>>(bsum, NB);
  scan3_kernel<<<NB, 256, 0, stream>>>(off, bsum, M, E);
  scatter_kernel<<<(E + 255) / 256, 256, 0, stream>>>(e_src, e_dst, off, cursor, sidx, E);

  // ---- conversions ----
  {
    int n4 = M * FDIM / 4;
    split_kernel<<<(n4 + 255) / 256, 256, 0, stream>>>((const float4*)x, x_h, n4);
    wtconv_all_kernel<<<512, 256, 0, stream>>>(enc_w, g1_w, g2_w, lp1_w, we, w1, w2, wlp);
    attcomb_kernel<<<20, 256, 0, stream>>>(g1_w, g1_as, g1_ad, g2_w, g2_as, g2_ad, w1, w2);
  }

  const int GB = (M + 127) / 128;   // 391 row-blocks

  // ---- encoder: h = relu(x @ enc_w + b) ----
  mfma_gemm<256, 4, 1, false><<<dim3(1, GB), 256, 0, stream>>>(
      x_h, we, enc_b, nullptr, hh, nullptr, nullptr, M, HID);

  // ---- GAT layer 1: one GEMM (cols 0..255 + fused logits on last col-block) ----
  mfma_gemm<64, 4, 2, true><<<dim3(4, GB), 256, 0, stream>>>(
      hh, w1, nullptr, nullptr, hWh, a_s, a_d, M, FDIM);
  aggregate_kernel<<<(M * 64 + 255) / 256, 256, 0, stream>>>(
      hWh, sidx, off, a_s, a_d, g1_b, agg, M);

  // ---- GAT layer 2 ----
  mfma_gemm<256, 4, 2, true><<<dim3(4, GB), 256, 0, stream>>>(
      agg, w2, nullptr, nullptr, hWh, a_s, a_d, M, FDIM);
  aggregate_kernel<<<(M * 64 + 255) / 256, 256, 0, stream>>>(
      hWh, sidx, off, a_s, a_d, g2_b, agg, M);

  // ---- link predictor ----
  mfma_gemm<256, 4, 0, false><<<dim3(2, GB), 256, 0, stream>>>(
      agg, wlp, nullptr, uv, nullptr, nullptr, nullptr, M, 2 * HID);
  linkpred_kernel<<<(NE + 15) / 16, 256, 0, stream>>>(uv, esrc, edst, lp1_b, lp2_w, lp2_b,
                                                      lp3_w, lp3_b, out, NE);
}

// Round 10
// 517.555 us; speedup vs baseline: 1.2009x; 1.0332x over previous
//
#include <hip/hip_runtime.h>
#include <hip/hip_bf16.h>
#include <math.h>

#define NNODES 50000
#define HID    64
#define HEADS  4
#define FDIM   256   // HEADS*HID

typedef __attribute__((ext_vector_type(8))) _Float16 half8v;
typedef __attribute__((ext_vector_type(4))) _Float16 half4v;
typedef __attribute__((ext_vector_type(4))) float f32x4;

__device__ __forceinline__ float lrelu(float x) { return fmaxf(x, 0.2f * x); }

// ---------------- fused prep: x->f16, weight transposes, att-combined cols ----------------
// region 0: [0, n4)            split x (float4 -> half4)
// region 1: [n4, n4+16384)     enc_w  [256,64]  -> we [64][256]
// region 2: +16384..32768      g1_w   [64,256]  -> w1 [256..][64] rows 0..255
// region 3: +32768..98304      g2_w   [256,256] -> w2 rows 0..255
// region 4: +98304..131072     lp1_w  [512,64]  -> wlp [128][256]
// region 5: +131072..132096    w1 rows 256..271 (att-combined, j>=8 zero)
// region 6: +132096..136192    w2 rows 256..271
__global__ void prep_kernel(const float4* __restrict__ x, _Float16* __restrict__ xh, int n4,
                            const float* __restrict__ enc_w, const float* __restrict__ g1_w,
                            const float* __restrict__ g2_w, const float* __restrict__ lp1_w,
                            const float* __restrict__ g1_as, const float* __restrict__ g1_ad,
                            const float* __restrict__ g2_as, const float* __restrict__ g2_ad,
                            _Float16* __restrict__ we, _Float16* __restrict__ w1,
                            _Float16* __restrict__ w2, _Float16* __restrict__ wlp)
{
  int t = blockIdx.x * blockDim.x + threadIdx.x;
  if (t < n4) {
    float4 v = x[t];
    half4v o = {(_Float16)v.x, (_Float16)v.y, (_Float16)v.z, (_Float16)v.w};
    *(half4v*)(xh + (size_t)t * 4) = o;
    return;
  }
  int u = t - n4;
  if (u < 16384) {                       // enc: N=64,K=256
    int n = u >> 8, k = u & 255;
    we[u] = (_Float16)enc_w[(size_t)k * 64 + n];
  } else if (u < 32768) {                // g1: N=256,K=64
    int l = u - 16384; int n = l >> 6, k = l & 63;
    w1[l] = (_Float16)g1_w[(size_t)k * 256 + n];
  } else if (u < 98304) {                // g2: N=256,K=256
    int l = u - 32768; int n = l >> 8, k = l & 255;
    w2[l] = (_Float16)g2_w[(size_t)k * 256 + n];
  } else if (u < 131072) {               // lp stacked: N=128,K=256
    int l = u - 98304; int n = l >> 8, k = l & 255;
    int srow = (n < 64) ? k : (256 + k);
    wlp[l] = (_Float16)lp1_w[(size_t)srow * 64 + (n & 63)];
  } else if (u < 132096) {               // w1 att rows, KTOT=64
    int l = u - 131072; int j = l >> 6, k = l & 63;
    float v = 0.f;
    if (j < 8) {
      int head = j & 3;
      const float* att = (j < 4 ? g1_as : g1_ad) + head * 64;
      for (int c = 0; c < 64; ++c) v += g1_w[(size_t)k * 256 + head * 64 + c] * att[c];
    }
    w1[(256 + j) * 64 + k] = (_Float16)v;
  } else if (u < 136192) {               // w2 att rows, KTOT=256
    int l = u - 132096; int j = l >> 8, k = l & 255;
    float v = 0.f;
    if (j < 8) {
      int head = j & 3;
      const float* att = (j < 4 ? g2_as : g2_ad) + head * 64;
      for (int c = 0; c < 64; ++c) v += g2_w[(size_t)k * 256 + head * 64 + c] * att[c];
    }
    w2[(256 + j) * 256 + k] = (_Float16)v;
  }
}

// ---------------- encoder GEMM (BM=128, BN=64, 256 thr): bias+relu f16 out ----------------
__global__ __launch_bounds__(256) void enc_gemm(
    const _Float16* __restrict__ A, const _Float16* __restrict__ B,
    const float* __restrict__ bias, _Float16* __restrict__ outH, int M)
{
  __shared__ _Float16 As[128 * 64];
  const int tid  = threadIdx.x;
  const int lane = tid & 63;
  const int wid  = tid >> 6;
  const int row0 = blockIdx.y * 128;

  f32x4 acc[2][4];
#pragma unroll
  for (int m = 0; m < 2; ++m)
#pragma unroll
    for (int n = 0; n < 4; ++n) acc[m][n] = (f32x4){0.f, 0.f, 0.f, 0.f};

  const int rsub = lane >> 3;
  const int slot = lane & 7;
  const int brow = lane & 15;
  const int bk   = (lane >> 4) * 8;

  for (int kt = 0; kt < 256; kt += 64) {
#pragma unroll
    for (int i = 0; i < 4; ++i) {
      const int c  = i * 4 + wid;
      const int r  = c * 8 + rsub;
      const int gr = min(row0 + r, M - 1);
      const int ss = slot ^ rsub;
      const size_t goff = (size_t)gr * 256 + kt + ss * 8;
      __builtin_amdgcn_global_load_lds(
          (const __attribute__((address_space(1))) void*)(A + goff),
          (__attribute__((address_space(3))) void*)(As + c * 512), 16, 0, 0);
    }
    __syncthreads();

#pragma unroll
    for (int ks = 0; ks < 2; ++ks) {
      half8v ah[2], bh[4];
#pragma unroll
      for (int mf = 0; mf < 2; ++mf) {
        const int r   = wid * 32 + mf * 16 + (lane & 15);
        const int sl  = (ks * 4 + (lane >> 4)) ^ (r & 7);
        ah[mf] = *(const half8v*)(As + r * 64 + sl * 8);
      }
#pragma unroll
      for (int nf = 0; nf < 4; ++nf)
        bh[nf] = *(const half8v*)(B + (size_t)(brow + nf * 16) * 256 + kt + ks * 32 + bk);
#pragma unroll
      for (int mf = 0; mf < 2; ++mf)
#pragma unroll
        for (int nf = 0; nf < 4; ++nf)
          acc[mf][nf] = __builtin_amdgcn_mfma_f32_16x16x32_f16(ah[mf], bh[nf], acc[mf][nf], 0, 0, 0);
    }
    __syncthreads();
  }

  const int crow = row0 + wid * 32 + (lane >> 4) * 4;
  const int ccol = lane & 15;
#pragma unroll
  for (int mf = 0; mf < 2; ++mf)
#pragma unroll
    for (int nf = 0; nf < 4; ++nf)
#pragma unroll
      for (int r = 0; r < 4; ++r) {
        const int grow = crow + mf * 16 + r;
        const int gcol = ccol + nf * 16;
        if (grow >= M) continue;
        float v = fmaxf(acc[mf][nf][r] + bias[gcol], 0.f);
        outH[(size_t)grow * HID + gcol] = (_Float16)v;
      }
}

// ---------------- gemm512: BM=128, BN=128, 512 thr, whole-K staged once ----------------
// 8 waves = 4 row-groups x 2 col-groups. One barrier per block. f16 out stride OS.
// LOGIT: colg==1 waves of the LAST x-block also compute B row 256..271 -> a_s/a_d.
template<int KTOT, bool LOGIT>
__global__ __launch_bounds__(512) void gemm512(
    const _Float16* __restrict__ A, const _Float16* __restrict__ B,
    _Float16* __restrict__ outH, float* __restrict__ a_s, float* __restrict__ a_d,
    int M, int OS)
{
  __shared__ _Float16 As[128 * KTOT];
  constexpr int SPR = KTOT / 8;            // 16B slots per LDS row
  const int tid  = threadIdx.x;
  const int lane = tid & 63;
  const int w    = tid >> 6;
  const int rowg = w & 3;
  const int colg = w >> 2;
  const int row0 = blockIdx.y * 128;
  const int col0 = blockIdx.x * 128 + colg * 64;
  const bool lastlog = LOGIT && ((int)blockIdx.x == (int)gridDim.x - 1) && (colg == 1);

  // ---- stage whole 128 x KTOT panel (swizzled source, linear dest) ----
#pragma unroll
  for (int rr = 0; rr < KTOT / 32; ++rr) {
    const int f  = rr * 512 + tid;
    const int r  = f / SPR;
    const int s  = f % SPR;
    const int gs = s ^ (r & 7);
    const int gr = min(row0 + r, M - 1);
    __builtin_amdgcn_global_load_lds(
        (const __attribute__((address_space(1))) void*)(A + (size_t)gr * KTOT + gs * 8),
        (__attribute__((address_space(3))) void*)(As + f * 8), 16, 0, 0);
  }
  __syncthreads();

  f32x4 acc[2][4];
  f32x4 accL[2];
#pragma unroll
  for (int m = 0; m < 2; ++m) {
#pragma unroll
    for (int n = 0; n < 4; ++n) acc[m][n] = (f32x4){0.f, 0.f, 0.f, 0.f};
    accL[m] = (f32x4){0.f, 0.f, 0.f, 0.f};
  }

  const int brow = col0 + (lane & 15);
#pragma unroll
  for (int ks = 0; ks < KTOT / 32; ++ks) {
    const int sk = ks * 4 + (lane >> 4);
    half8v ah[2];
#pragma unroll
    for (int mf = 0; mf < 2; ++mf) {
      const int r = rowg * 32 + mf * 16 + (lane & 15);
      ah[mf] = *(const half8v*)(As + r * KTOT + (sk ^ (r & 7)) * 8);
    }
#pragma unroll
    for (int nf = 0; nf < 4; ++nf) {
      const half8v bh = *(const half8v*)(B + (size_t)(brow + nf * 16) * KTOT + sk * 8);
      acc[0][nf] = __builtin_amdgcn_mfma_f32_16x16x32_f16(ah[0], bh, acc[0][nf], 0, 0, 0);
      acc[1][nf] = __builtin_amdgcn_mfma_f32_16x16x32_f16(ah[1], bh, acc[1][nf], 0, 0, 0);
    }
    if (lastlog) {
      const half8v bh = *(const half8v*)(B + (size_t)(256 + (lane & 15)) * KTOT + sk * 8);
      accL[0] = __builtin_amdgcn_mfma_f32_16x16x32_f16(ah[0], bh, accL[0], 0, 0, 0);
      accL[1] = __builtin_amdgcn_mfma_f32_16x16x32_f16(ah[1], bh, accL[1], 0, 0, 0);
    }
  }

  // ---- epilogue: C/D layout col=lane&15, row=(lane>>4)*4+reg ----
  const int crow = row0 + rowg * 32 + (lane >> 4) * 4;
  const int ccol = col0 + (lane & 15);
#pragma unroll
  for (int mf = 0; mf < 2; ++mf)
#pragma unroll
    for (int nf = 0; nf < 4; ++nf)
#pragma unroll
      for (int r = 0; r < 4; ++r) {
        const int grow = crow + mf * 16 + r;
        if (grow >= M) continue;
        outH[(size_t)grow * OS + ccol + nf * 16] = (_Float16)acc[mf][nf][r];
      }
  if (lastlog) {
    const int c8 = lane & 15;
#pragma unroll
    for (int mf = 0; mf < 2; ++mf)
#pragma unroll
      for (int r = 0; r < 4; ++r) {
        const int grow = crow + mf * 16 + r;
        if (grow >= M) continue;
        const float v = accL[mf][r];
        if (c8 < 4)      a_s[grow * 4 + c8] = v;
        else if (c8 < 8) a_d[grow * 4 + (c8 - 4)] = v;
      }
  }
}

// ---------------- CSR build ----------------
__global__ void hist_kernel(const int* __restrict__ dst, int* __restrict__ deg, int E)
{
  int i = blockIdx.x * blockDim.x + threadIdx.x;
  if (i < E) atomicAdd(&deg[dst[i]], 1);
}

__global__ void scan1_kernel(const int* __restrict__ deg, int* __restrict__ off,
                             int* __restrict__ bsum, int n)
{
  __shared__ int ws[4];
  const int t = threadIdx.x, lane = t & 63, w = t >> 6;
  const int i = blockIdx.x * 256 + t;
  const int v = (i < n) ? deg[i] : 0;
  int x = v;
#pragma unroll
  for (int d = 1; d < 64; d <<= 1) {
    int y = __shfl_up(x, d, 64);
    if (lane >= d) x += y;
  }
  if (lane == 63) ws[w] = x;
  __syncthreads();
  int add = 0;
  for (int k = 0; k < w; ++k) add += ws[k];
  if (i < n) off[i] = add + x - v;
  if (t == 255) bsum[blockIdx.x] = add + x;
}

__global__ void scan2_kernel(int* __restrict__ bsum, int nb)
{
  __shared__ int ws[4];
  const int t = threadIdx.x, lane = t & 63, w = t >> 6;
  const int v = (t < nb) ? bsum[t] : 0;
  int x = v;
#pragma unroll
  for (int d = 1; d < 64; d <<= 1) {
    int y = __shfl_up(x, d, 64);
    if (lane >= d) x += y;
  }
  if (lane == 63) ws[w] = x;
  __syncthreads();
  int add = 0;
  for (int k = 0; k < w; ++k) add += ws[k];
  if (t < nb) bsum[t] = add + x - v;
}

__global__ void scan3_kernel(int* __restrict__ off, const int* __restrict__ bsum, int n, int E)
{
  const int i = blockIdx.x * 256 + threadIdx.x;
  if (i < n) off[i] += bsum[blockIdx.x];
  if (i == 0) off[n] = E;
}

__global__ void scatter_kernel(const int* __restrict__ src, const int* __restrict__ dst,
                               const int* __restrict__ off, int* __restrict__ cursor,
                               int* __restrict__ sidx, int E)
{
  int i = blockIdx.x * blockDim.x + threadIdx.x;
  if (i < E) {
    int d = dst[i];
    int p = atomicAdd(&cursor[d], 1);
    sidx[off[d] + p] = src[i];
  }
}

// ---------------- GAT aggregation: one wave per dst node (f16 messages) ----------------
__global__ __launch_bounds__(256) void aggregate_kernel(
    const _Float16* __restrict__ hW, const int* __restrict__ sidx,
    const int* __restrict__ off, const float* __restrict__ a_s, const float* __restrict__ a_d,
    const float* __restrict__ bias,
    _Float16* __restrict__ outH, int n_nodes)
{
  __shared__ float wlds[4][16][4];
  const int w    = threadIdx.x >> 6;
  const int wid  = (blockIdx.x * 256 + threadIdx.x) >> 6;
  const int lane = threadIdx.x & 63;
  if (wid >= n_nodes) return;
  const int n = wid;
  const int beg = off[n], end = off[n + 1];

  // ---- Phase A: online (m, s) per head ----
  const int es   = lane >> 2;    // edge slot 0..15
  const int hh   = lane & 3;     // head
  const float adh = a_d[(unsigned)n * 4 + hh];
  float m = -1e30f, ssum = 0.f;
  for (int j = beg + es; j < end; j += 16) {
    const unsigned s = (unsigned)sidx[j];
    const float e = lrelu(a_s[s * 4 + hh] + adh);
    const float mn = fmaxf(m, e);
    ssum = ssum * __expf(m - mn) + __expf(e - mn);
    m = mn;
  }
#pragma unroll
  for (int d = 4; d < 64; d <<= 1) {
    const float mo = __shfl_xor(m, d, 64);
    const float so = __shfl_xor(ssum, d, 64);
    const float mn = fmaxf(m, mo);
    ssum = ssum * __expf(m - mn) + so * __expf(mo - mn);
    m = mn;
  }
  const int hb = lane >> 4;                    // head this lane accumulates in B
  const float sh = __shfl(ssum, hb, 64);

  // ---- Phase B: chunked, weights via LDS broadcast ----
  float acc0 = 0.f, acc1 = 0.f, acc2 = 0.f, acc3 = 0.f;
  const unsigned lo4 = (unsigned)(lane << 2);
  for (int j0 = beg; j0 < end; j0 += 16) {
    const int jj = j0 + es;
    float wv = 0.f;
    if (jj < end) {
      const unsigned s = (unsigned)sidx[jj];
      const float e = lrelu(a_s[s * 4 + hh] + adh);
      wv = __expf(e - m);
    }
    wlds[w][es][hh] = wv;
    const int jend = min(j0 + 16, end);
#pragma unroll 4
    for (int j = j0; j < jend; ++j) {
      const unsigned s = (unsigned)sidx[j];
      const float wgt = wlds[w][j - j0][hb];
      const half4v hv = *(const half4v*)(hW + s * (unsigned)FDIM + lo4);
      acc0 = fmaf(wgt, (float)hv.x, acc0);
      acc1 = fmaf(wgt, (float)hv.y, acc1);
      acc2 = fmaf(wgt, (float)hv.z, acc2);
      acc3 = fmaf(wgt, (float)hv.w, acc3);
    }
  }
  const float inv = 1.f / (sh + 1e-16f);
  const float4 bv = *(const float4*)(bias + lo4);
  half4v o = {(_Float16)(acc0 * inv + bv.x), (_Float16)(acc1 * inv + bv.y),
              (_Float16)(acc2 * inv + bv.z), (_Float16)(acc3 * inv + bv.w)};
  *(half4v*)(outH + (unsigned)n * FDIM + lo4) = o;
}

// ---------------- link predictor: 16 pairs/block, 4 per wave (f16 uv) ----------------
__global__ __launch_bounds__(256) void linkpred_kernel(
    const _Float16* __restrict__ uv,
    const int* __restrict__ es, const int* __restrict__ ed,
    const float* __restrict__ b1, const float* __restrict__ w2, const float* __restrict__ b2,
    const float* __restrict__ w3, const float* __restrict__ b3,
    float* __restrict__ out, int n_eval)
{
  __shared__ float w2s[64 * 32];
  __shared__ float z1s[4][4][64];
  const int t = threadIdx.x;
  for (int i = t; i < 64 * 32; i += 256) w2s[i] = w2[i];
  const int w = t >> 6, lane = t & 63;
  const int pair0 = blockIdx.x * 16 + w * 4;
#pragma unroll
  for (int p = 0; p < 4; ++p) {
    const int pc = min(pair0 + p, n_eval - 1);
    const int s = es[pc], d = ed[pc];
    const float uvl = (float)uv[(unsigned)s * 128 + lane] + (float)uv[(unsigned)d * 128 + 64 + lane];
    z1s[w][p][lane] = fmaxf(uvl + b1[lane], 0.f);
  }
  __syncthreads();
  const int half = lane >> 5;
  const int col  = lane & 31;
  const float w3c = w3[col];
#pragma unroll
  for (int pp = 0; pp < 2; ++pp) {
    const int p = pp * 2 + half;
    float acc = b2[col];
#pragma unroll
    for (int k = 0; k < 64; ++k) acc = fmaf(z1s[w][p][k], w2s[k * 32 + col], acc);
    float zz = fmaxf(acc, 0.f) * w3c;
#pragma unroll
    for (int d = 1; d < 32; d <<= 1) zz += __shfl_xor(zz, d, 64);
    if (col == 0) {
      const int pv = pair0 + p;
      if (pv < n_eval) out[pv] = zz + b3[0];
    }
  }
}

// ---------------- launch ----------------
extern "C" void kernel_launch(void* const* d_in, const int* in_sizes, int n_in,
                              void* d_out, int out_size, void* d_ws, size_t ws_size,
                              hipStream_t stream)
{
  const float* x     = (const float*)d_in[0];
  const int*   ei    = (const int*)d_in[1];
  const int*   esrc  = (const int*)d_in[2];
  const int*   edst  = (const int*)d_in[3];
  const float* enc_w = (const float*)d_in[4];
  const float* enc_b = (const float*)d_in[5];
  const float* g1_w  = (const float*)d_in[6];
  const float* g1_as = (const float*)d_in[7];
  const float* g1_ad = (const float*)d_in[8];
  const float* g1_b  = (const float*)d_in[9];
  const float* g2_w  = (const float*)d_in[10];
  const float* g2_as = (const float*)d_in[11];
  const float* g2_ad = (const float*)d_in[12];
  const float* g2_b  = (const float*)d_in[13];
  const float* lp1_w = (const float*)d_in[14];
  const float* lp1_b = (const float*)d_in[15];
  const float* lp2_w = (const float*)d_in[16];
  const float* lp2_b = (const float*)d_in[17];
  const float* lp3_w = (const float*)d_in[18];
  const float* lp3_b = (const float*)d_in[19];
  float* out = (float*)d_out;

  const int E  = in_sizes[1] / 2;   // 1,000,000
  const int NE = in_sizes[2];       // 100,000
  const int M  = NNODES;
  const int NB = (M + 255) / 256;   // scan blocks

  const int* e_src = ei;
  const int* e_dst = ei + E;

  // ---- workspace layout ----
  _Float16* hWh = (_Float16*)d_ws;                     // M*256 f16 (alias uv f16 M*128)
  float* a_s   = (float*)(hWh + (size_t)M * FDIM);     // M*4
  float* a_d   = a_s + (size_t)M * HEADS;              // M*4
  _Float16* hh = (_Float16*)(a_d + (size_t)M * HEADS); // M*64
  _Float16* agg = hh + (size_t)M * HID;                // M*256 (also x_h)
  int*   deg    = (int*)(agg + (size_t)M * FDIM);
  int*   cursor = deg + M;
  int*   off    = cursor + M;
  int*   bsum   = off + M + 1;                         // 256 ints
  int*   sidx   = bsum + 256;
  _Float16* we  = (_Float16*)(sidx + E);               // 64*256
  _Float16* w1  = we + 64 * 256;                       // 272*64
  _Float16* w2  = w1 + 272 * 64;                       // 272*256
  _Float16* wlp = w2 + 272 * 256;                      // 128*256
  _Float16* x_h = agg;       // x plane dead after encoder; agg written later
  _Float16* uv = hWh;        // hWh dead after aggregate2; uv = M*128 f16

  // ---- CSR build ----
  hipMemsetAsync(deg, 0, sizeof(int) * 2 * (size_t)M, stream);
  hist_kernel<<<(E + 255) / 256, 256, 0, stream>>>(e_dst, deg, E);
  scan1_kernel<<<NB, 256, 0, stream>>>(deg, off, bsum, M);
  scan2_kernel<<<1, 256, 0, stream>>>(bsum, NB);
  scan3_kernel<<<NB, 256, 0, stream>>>(off, bsum, M, E);
  scatter_kernel<<<(E + 255) / 256, 256, 0, stream>>>(e_src, e_dst, off, cursor, sidx, E);

  // ---- fused prep (split + all weight conversions) ----
  {
    const int n4 = M * FDIM / 4;                       // 3,200,000
    const int total = n4 + 136192;
    prep_kernel<<<(total + 255) / 256, 256, 0, stream>>>(
        (const float4*)x, x_h, n4, enc_w, g1_w, g2_w, lp1_w,
        g1_as, g1_ad, g2_as, g2_ad, we, w1, w2, wlp);
  }

  const int GB = (M + 127) / 128;   // 391 row-blocks

  // ---- encoder: h = relu(x @ enc_w + b) ----
  enc_gemm<<<dim3(1, GB), 256, 0, stream>>>(x_h, we, enc_b, hh, M);

  // ---- GAT layer 1: gemm512 (256 cols + fused logits) + aggregate ----
  gemm512<64, true><<<dim3(2, GB), 512, 0, stream>>>(hh, w1, hWh, a_s, a_d, M, FDIM);
  aggregate_kernel<<<(M * 64 + 255) / 256, 256, 0, stream>>>(
      hWh, sidx, off, a_s, a_d, g1_b, agg, M);

  // ---- GAT layer 2 ----
  gemm512<256, true><<<dim3(2, GB), 512, 0, stream>>>(agg, w2, hWh, a_s, a_d, M, FDIM);
  aggregate_kernel<<<(M * 64 + 255) / 256, 256, 0, stream>>>(
      hWh, sidx, off, a_s, a_d, g2_b, agg, M);

  // ---- link predictor ----
  gemm512<256, false><<<dim3(1, GB), 512, 0, stream>>>(agg, wlp, uv, nullptr, nullptr, M, 2 * HID);
  linkpred_kernel<<<(NE + 15) / 16, 256, 0, stream>>>(uv, esrc, edst, lp1_b, lp2_w, lp2_b,
                                                      lp3_w, lp3_b, out, NE);
}